// Round 1
// baseline (28896.902 us; speedup 1.0000x reference)
//
#include <hip/hip_runtime.h>

#define N 128
#define PAD 129
#define NL 8128
#define POWER_IT 32
#define INV_IT 12
#define NTHREADS 256

// LDS float counts
#define MATF (2 * N * PAD)            // Ahi + Alo = 33024 floats
#define DBLN 704                      // doubles after matrix
#define FLTN 1088                     // floats after doubles
#define SMEM_BYTES (MATF*4 + DBLN*8 + FLTN*4 + 16)

static __device__ __forceinline__ double ldD(const float* hi, const float* lo, int idx) {
    return (double)hi[idx] + (double)lo[idx];
}
static __device__ __forceinline__ void stD(float* hi, float* lo, int idx, double v) {
    float h = (float)v;
    hi[idx] = h;
    lo[idx] = (float)(v - (double)h);
}
static __device__ __forceinline__ float hashf(unsigned x) {
    x ^= 2747636419u; x *= 2654435769u; x ^= x >> 16;
    x *= 2654435769u; x ^= x >> 16; x *= 2654435769u;
    return ((float)(x >> 8)) * (1.0f / 16777216.0f) - 0.5f;
}

// Cholesky of 4x4 Gram (packed upper, 10 entries) -> C = R^{-1} (upper, row-major 4x4)
static __device__ void cholInvC(const double* Gp, double* C) {
    double g[4][4];
    int c = 0;
    for (int a = 0; a < 4; ++a)
        for (int b2 = a; b2 < 4; ++b2) { g[a][b2] = Gp[c]; g[b2][a] = Gp[c]; ++c; }
    double R[4][4];
    for (int i = 0; i < 4; ++i) {
        double d = g[i][i];
        for (int m = 0; m < i; ++m) d -= R[m][i] * R[m][i];
        d = sqrt(fmax(d, 1e-300));
        R[i][i] = d;
        for (int j = i + 1; j < 4; ++j) {
            double v = g[i][j];
            for (int m = 0; m < i; ++m) v -= R[m][i] * R[m][j];
            R[i][j] = v / d;
        }
    }
    for (int j = 3; j >= 0; --j) {
        C[j*4 + j] = 1.0 / R[j][j];
        for (int i = j - 1; i >= 0; --i) {
            double v = 0.0;
            for (int m = i + 1; m <= j; ++m) v += R[i][m] * C[m*4 + j];
            C[i*4 + j] = -v / R[i][i];
        }
        for (int i = j + 1; i < 4; ++i) C[i*4 + j] = 0.0;
    }
}

// symmetric 4x4 Jacobi eigenvalues (diagonal afterwards)
static __device__ void jacobi4(double g[4][4]) {
    for (int sweep = 0; sweep < 6; ++sweep) {
        for (int p = 0; p < 3; ++p) {
            for (int q = p + 1; q < 4; ++q) {
                double apq = g[p][q];
                if (fabs(apq) < 1e-300) continue;
                double tau = (g[q][q] - g[p][p]) / (2.0 * apq);
                double t = (tau >= 0.0 ? 1.0 : -1.0) / (fabs(tau) + sqrt(1.0 + tau * tau));
                double cc = 1.0 / sqrt(1.0 + t * t);
                double ss = t * cc;
                for (int r = 0; r < 4; ++r) {
                    double grp = g[r][p], grq = g[r][q];
                    g[r][p] = cc * grp - ss * grq;
                    g[r][q] = ss * grp + cc * grq;
                }
                for (int r = 0; r < 4; ++r) {
                    double gpr = g[p][r], gqr = g[q][r];
                    g[p][r] = cc * gpr - ss * gqr;
                    g[q][r] = ss * gpr + cc * gqr;
                }
            }
        }
    }
}

__global__ __launch_bounds__(NTHREADS, 1)
void cond_kernel(const float* __restrict__ DD, const float* __restrict__ LE,
                 const float* __restrict__ SCL, double* __restrict__ conds)
{
    extern __shared__ float sm[];
    float* Ahi = sm;
    float* Alo = sm + N * PAD;
    double* dsc   = (double*)(sm + MATF);
    double* dY    = dsc;          // 512
    double* dinvd = dsc + 512;    // 128
    double* dred  = dsc + 640;    // 32
    double* dG    = dsc + 672;    // 16
    double* dmisc = dsc + 688;    // 16
    float*  fsc  = (float*)(dsc + DBLN);
    float*  fX   = fsc;           // 512
    float*  fW   = fsc + 512;     // 512
    float*  fred = fsc + 1024;    // 64
    int*    iscr = (int*)(fsc + FLTN);   // 4 ints

    const int tid = threadIdx.x;
    const int b   = blockIdx.x;
    const double s = (double)SCL[0];
    const float* dd = DD + (size_t)b * (N * N);
    const float* le = LE + (size_t)b * NL;

    // ---- stage DD into (Ahi, Alo=0)
    for (int t = tid; t < N * N; t += NTHREADS) {
        int i = t >> 7, j = t & 127;
        Ahi[i * PAD + j] = dd[t];
        Alo[i * PAD + j] = 0.0f;
    }
    __syncthreads();

    const int half = tid >> 7;
    const int jcol = tid & 127;

    // ---- Pass A: A <- L^T * A (ascending k). rows i>k are still raw fp32 DD (lo=0).
    #pragma unroll 1
    for (int k = 0; k < N - 1; ++k) {
        int i0 = k + 1, i1 = N;
        int mid = (i0 + i1) >> 1;
        int a0 = half ? mid : i0;
        int a1 = half ? i1 : mid;
        double acc = 0.0;
        int off = a0 * (a0 - 1) / 2 + k;
        #pragma unroll 4
        for (int i = a0; i < a1; ++i) {
            acc += (double)le[off] * (double)Ahi[i * PAD + jcol];
            off += i;
        }
        dY[half * 128 + jcol] = acc;
        __syncthreads();
        if (half == 0) {
            double v = (double)Ahi[k * PAD + jcol] + s * (dY[jcol] + dY[128 + jcol]);
            stD(Ahi, Alo, k * PAD + jcol, v);
        }
        __syncthreads();
    }

    // ---- Pass B: A <- L * A (descending i)
    #pragma unroll 1
    for (int i = N - 1; i >= 1; --i) {
        int mid = i >> 1;
        int m0 = half ? mid : 0;
        int m1 = half ? i : mid;
        const float* er = le + i * (i - 1) / 2;
        double acc = 0.0;
        #pragma unroll 4
        for (int m = m0; m < m1; ++m)
            acc += (double)er[m] * ldD(Ahi, Alo, m * PAD + jcol);
        dY[half * 128 + jcol] = acc;
        __syncthreads();
        if (half == 0) {
            double v = ldD(Ahi, Alo, i * PAD + jcol) + s * (dY[jcol] + dY[128 + jcol]);
            stD(Ahi, Alo, i * PAD + jcol, v);
        }
        __syncthreads();
    }

    // ---- LU with partial pivoting, in place, fp64 (hi/lo)
    #pragma unroll 1
    for (int k = 0; k < N - 1; ++k) {
        float v = -1.0f; int idx = k;
        if (tid < 128 && tid >= k) { v = fabsf(Ahi[tid * PAD + k]); idx = tid; }
        if (tid < 128) {
            #pragma unroll
            for (int o = 32; o > 0; o >>= 1) {
                float ov = __shfl_xor(v, o);
                int   oi = __shfl_xor(idx, o);
                if (ov > v) { v = ov; idx = oi; }
            }
            if ((tid & 63) == 0) { fred[tid >> 6] = v; iscr[tid >> 6] = idx; }
        }
        __syncthreads();
        if (tid == 0) iscr[2] = (fred[0] >= fred[1]) ? iscr[0] : iscr[1];
        __syncthreads();
        int p = iscr[2];
        if (p != k && tid < 128) {
            int j = tid;
            float th = Ahi[k * PAD + j], tl = Alo[k * PAD + j];
            Ahi[k * PAD + j] = Ahi[p * PAD + j]; Alo[k * PAD + j] = Alo[p * PAD + j];
            Ahi[p * PAD + j] = th;               Alo[p * PAD + j] = tl;
        }
        __syncthreads();
        if (tid == 0) dinvd[k] = 1.0 / ldD(Ahi, Alo, k * PAD + k);
        __syncthreads();
        double invd = dinvd[k];
        int g  = tid >> 5;
        int lj = tid & 31;
        double ukj[4]; int jjs[4]; int nj = 0;
        for (int j = k + 1 + lj; j < N; j += 32) { ukj[nj] = ldD(Ahi, Alo, k * PAD + j); jjs[nj] = j; ++nj; }
        #pragma unroll 1
        for (int i = k + 1 + g; i < N; i += 8) {
            double lik = ldD(Ahi, Alo, i * PAD + k) * invd;
            if (lj == 0) stD(Ahi, Alo, i * PAD + k, lik);
            for (int t2 = 0; t2 < nj; ++t2) {
                int j = jjs[t2];
                stD(Ahi, Alo, i * PAD + j, ldD(Ahi, Alo, i * PAD + j) - lik * ukj[t2]);
            }
        }
        __syncthreads();
    }
    if (tid == 0) dinvd[N - 1] = 1.0 / ldD(Ahi, Alo, (N - 1) * PAD + (N - 1));
    __syncthreads();

    const int w  = tid >> 6;
    const int l  = tid & 63;
    const int r0 = 2 * l, r1 = 2 * l + 1;

    // ---- block-4 power iteration on P^T P = U^T L^T L U (fp32, hi only)
    fX[w * 128 + r0] = hashf((unsigned)(w * 997 + r0 * 7919 + 13));
    fX[w * 128 + r1] = hashf((unsigned)(w * 997 + r1 * 7919 + 13));
    #pragma unroll 1
    for (int it = 0; it < POWER_IT; ++it) {
        float t0 = 0.f, t1 = 0.f;
        #pragma unroll 4
        for (int j = 0; j < N; ++j) {
            float xj = fX[w * 128 + j];
            if (j >= r0) t0 += Ahi[r0 * PAD + j] * xj;
            if (j >= r1) t1 += Ahi[r1 * PAD + j] * xj;
        }
        fW[w * 128 + r0] = t0; fW[w * 128 + r1] = t1;
        float u0 = t0, u1 = t1;
        #pragma unroll 4
        for (int j = 0; j < N; ++j) {
            float tj = fW[w * 128 + j];
            if (j < r0) u0 += Ahi[r0 * PAD + j] * tj;
            if (j < r1) u1 += Ahi[r1 * PAD + j] * tj;
        }
        fX[w * 128 + r0] = u0; fX[w * 128 + r1] = u1;
        float v0 = u0, v1 = u1;
        #pragma unroll 4
        for (int i = 0; i < N; ++i) {
            float ui = fX[w * 128 + i];
            if (i > r0) v0 += Ahi[i * PAD + r0] * ui;
            if (i > r1) v1 += Ahi[i * PAD + r1] * ui;
        }
        fW[w * 128 + r0] = v0; fW[w * 128 + r1] = v1;
        float z0 = 0.f, z1 = 0.f;
        #pragma unroll 4
        for (int i = 0; i < N; ++i) {
            float vi = fW[w * 128 + i];
            if (i <= r0) z0 += Ahi[i * PAD + r0] * vi;
            if (i <= r1) z1 += Ahi[i * PAD + r1] * vi;
        }
        float n2 = z0 * z0 + z1 * z1;
        #pragma unroll
        for (int o = 32; o > 0; o >>= 1) n2 += __shfl_xor(n2, o);
        float inz = rsqrtf(n2 + 1e-30f);
        fX[w * 128 + r0] = z0 * inz; fX[w * 128 + r1] = z1 * inz;
        if ((it & 1) == 1) {
            __syncthreads();
            if (tid < 128) {
                float x0 = fX[tid], x1 = fX[128 + tid], x2 = fX[256 + tid], x3 = fX[384 + tid];
                double pr[10] = { (double)x0*x0, (double)x0*x1, (double)x0*x2, (double)x0*x3,
                                  (double)x1*x1, (double)x1*x2, (double)x1*x3,
                                  (double)x2*x2, (double)x2*x3, (double)x3*x3 };
                #pragma unroll
                for (int o = 32; o > 0; o >>= 1)
                    for (int c = 0; c < 10; ++c) pr[c] += __shfl_xor(pr[c], o);
                if ((tid & 63) == 0)
                    for (int c = 0; c < 10; ++c) dred[(tid >> 6) * 10 + c] = pr[c];
            }
            __syncthreads();
            if (tid == 0) {
                double Gp[10];
                for (int c = 0; c < 10; ++c) Gp[c] = dred[c] + dred[10 + c];
                cholInvC(Gp, dG);
            }
            __syncthreads();
            if (tid < 128) {
                float x0 = fX[tid], x1 = fX[128 + tid], x2 = fX[256 + tid], x3 = fX[384 + tid];
                fX[tid]       = (float)(dG[0]*x0);
                fX[128 + tid] = (float)(dG[1]*x0 + dG[5]*x1);
                fX[256 + tid] = (float)(dG[2]*x0 + dG[6]*x1 + dG[10]*x2);
                fX[384 + tid] = (float)(dG[3]*x0 + dG[7]*x1 + dG[11]*x2 + dG[15]*x3);
            }
            __syncthreads();
        }
    }
    // Ritz for sigma_max: Z = L U X, lambda_max of Z^T Z
    {
        float t0 = 0.f, t1 = 0.f;
        #pragma unroll 4
        for (int j = 0; j < N; ++j) {
            float xj = fX[w * 128 + j];
            if (j >= r0) t0 += Ahi[r0 * PAD + j] * xj;
            if (j >= r1) t1 += Ahi[r1 * PAD + j] * xj;
        }
        fW[w * 128 + r0] = t0; fW[w * 128 + r1] = t1;
        float z0 = t0, z1 = t1;
        #pragma unroll 4
        for (int j = 0; j < N; ++j) {
            float tj = fW[w * 128 + j];
            if (j < r0) z0 += Ahi[r0 * PAD + j] * tj;
            if (j < r1) z1 += Ahi[r1 * PAD + j] * tj;
        }
        fX[w * 128 + r0] = z0; fX[w * 128 + r1] = z1;
        __syncthreads();
        if (tid < 128) {
            float x0 = fX[tid], x1 = fX[128 + tid], x2 = fX[256 + tid], x3 = fX[384 + tid];
            double pr[10] = { (double)x0*x0, (double)x0*x1, (double)x0*x2, (double)x0*x3,
                              (double)x1*x1, (double)x1*x2, (double)x1*x3,
                              (double)x2*x2, (double)x2*x3, (double)x3*x3 };
            #pragma unroll
            for (int o = 32; o > 0; o >>= 1)
                for (int c = 0; c < 10; ++c) pr[c] += __shfl_xor(pr[c], o);
            if ((tid & 63) == 0)
                for (int c = 0; c < 10; ++c) dred[(tid >> 6) * 10 + c] = pr[c];
        }
        __syncthreads();
        if (tid == 0) {
            double Gp[10];
            for (int c = 0; c < 10; ++c) Gp[c] = dred[c] + dred[10 + c];
            double g[4][4]; int c2 = 0;
            for (int a = 0; a < 4; ++a)
                for (int b2 = a; b2 < 4; ++b2) { g[a][b2] = Gp[c2]; g[b2][a] = Gp[c2]; ++c2; }
            jacobi4(g);
            double lmax = fmax(fmax(g[0][0], g[1][1]), fmax(g[2][2], g[3][3]));
            dmisc[0] = sqrt(fmax(lmax, 0.0));
        }
        __syncthreads();
    }

    // ---- block-4 inverse iteration (fp64): y <- (U^T L^T L U)^{-1} y
    {
        double y0 = (double)hashf((unsigned)(w * 337 + r0 * 101 + 7777));
        double y1 = (double)hashf((unsigned)(w * 337 + r1 * 101 + 7777));
        #pragma unroll 1
        for (int it = 0; it < INV_IT; ++it) {
            // U^T a = y (ascending)
            #pragma unroll 1
            for (int i = 0; i < N; ++i) {
                double c = ((i & 1) ? y1 : y0) * dinvd[i];
                double a = __shfl(c, i >> 1);
                if (r0 > i) y0 -= ldD(Ahi, Alo, i * PAD + r0) * a;
                if (r1 > i) y1 -= ldD(Ahi, Alo, i * PAD + r1) * a;
                if ((i >> 1) == l) { if (i & 1) y1 = a; else y0 = a; }
            }
            // L^T b = a (descending, unit diag)
            #pragma unroll 1
            for (int j = N - 1; j >= 0; --j) {
                double c = (j & 1) ? y1 : y0;
                double bj = __shfl(c, j >> 1);
                if (r0 < j) y0 -= ldD(Ahi, Alo, j * PAD + r0) * bj;
                if (r1 < j) y1 -= ldD(Ahi, Alo, j * PAD + r1) * bj;
            }
            // L c = b (ascending, unit diag)
            #pragma unroll 1
            for (int j = 0; j < N; ++j) {
                double c = (j & 1) ? y1 : y0;
                double cj = __shfl(c, j >> 1);
                if (r0 > j) y0 -= ldD(Ahi, Alo, r0 * PAD + j) * cj;
                if (r1 > j) y1 -= ldD(Ahi, Alo, r1 * PAD + j) * cj;
            }
            // U x = c (descending)
            #pragma unroll 1
            for (int i = N - 1; i >= 0; --i) {
                double c = ((i & 1) ? y1 : y0) * dinvd[i];
                double xi = __shfl(c, i >> 1);
                if (r0 < i) y0 -= ldD(Ahi, Alo, r0 * PAD + i) * xi;
                if (r1 < i) y1 -= ldD(Ahi, Alo, r1 * PAD + i) * xi;
                if ((i >> 1) == l) { if (i & 1) y1 = xi; else y0 = xi; }
            }
            // orthonormalize 4 vectors (fp64)
            dY[w * 128 + r0] = y0; dY[w * 128 + r1] = y1;
            __syncthreads();
            if (tid < 128) {
                double x0 = dY[tid], x1 = dY[128 + tid], x2 = dY[256 + tid], x3 = dY[384 + tid];
                double pr[10] = { x0*x0, x0*x1, x0*x2, x0*x3, x1*x1, x1*x2, x1*x3, x2*x2, x2*x3, x3*x3 };
                #pragma unroll
                for (int o = 32; o > 0; o >>= 1)
                    for (int c = 0; c < 10; ++c) pr[c] += __shfl_xor(pr[c], o);
                if ((tid & 63) == 0)
                    for (int c = 0; c < 10; ++c) dred[(tid >> 6) * 10 + c] = pr[c];
            }
            __syncthreads();
            if (tid == 0) {
                double Gp[10];
                for (int c = 0; c < 10; ++c) Gp[c] = dred[c] + dred[10 + c];
                cholInvC(Gp, dG);
            }
            __syncthreads();
            if (tid < 128) {
                double x0 = dY[tid], x1 = dY[128 + tid], x2 = dY[256 + tid], x3 = dY[384 + tid];
                dY[tid]       = dG[0]*x0;
                dY[128 + tid] = dG[1]*x0 + dG[5]*x1;
                dY[256 + tid] = dG[2]*x0 + dG[6]*x1 + dG[10]*x2;
                dY[384 + tid] = dG[3]*x0 + dG[7]*x1 + dG[11]*x2 + dG[15]*x3;
            }
            __syncthreads();
            y0 = dY[w * 128 + r0]; y1 = dY[w * 128 + r1];
        }
        // Ritz for sigma_min: Z = L U Y (fp64), lambda_min of Z^T Z
        double t0 = 0.0, t1 = 0.0;
        #pragma unroll 1
        for (int j = 0; j < N; ++j) {
            double yj = dY[w * 128 + j];
            if (j >= r0) t0 += ldD(Ahi, Alo, r0 * PAD + j) * yj;
            if (j >= r1) t1 += ldD(Ahi, Alo, r1 * PAD + j) * yj;
        }
        dY[w * 128 + r0] = t0; dY[w * 128 + r1] = t1;
        double z0 = t0, z1 = t1;
        #pragma unroll 1
        for (int j = 0; j < N; ++j) {
            double tj = dY[w * 128 + j];
            if (j < r0) z0 += ldD(Ahi, Alo, r0 * PAD + j) * tj;
            if (j < r1) z1 += ldD(Ahi, Alo, r1 * PAD + j) * tj;
        }
        dY[w * 128 + r0] = z0; dY[w * 128 + r1] = z1;
        __syncthreads();
        if (tid < 128) {
            double x0 = dY[tid], x1 = dY[128 + tid], x2 = dY[256 + tid], x3 = dY[384 + tid];
            double pr[10] = { x0*x0, x0*x1, x0*x2, x0*x3, x1*x1, x1*x2, x1*x3, x2*x2, x2*x3, x3*x3 };
            #pragma unroll
            for (int o = 32; o > 0; o >>= 1)
                for (int c = 0; c < 10; ++c) pr[c] += __shfl_xor(pr[c], o);
            if ((tid & 63) == 0)
                for (int c = 0; c < 10; ++c) dred[(tid >> 6) * 10 + c] = pr[c];
        }
        __syncthreads();
        if (tid == 0) {
            double Gp[10];
            for (int c = 0; c < 10; ++c) Gp[c] = dred[c] + dred[10 + c];
            double g[4][4]; int c2 = 0;
            for (int a = 0; a < 4; ++a)
                for (int b2 = a; b2 < 4; ++b2) { g[a][b2] = Gp[c2]; g[b2][a] = Gp[c2]; ++c2; }
            jacobi4(g);
            double lmin = fmin(fmin(g[0][0], g[1][1]), fmin(g[2][2], g[3][3]));
            double smin = sqrt(fmax(lmin, 1e-300));
            conds[b] = dmisc[0] / smin;
        }
    }
}

__global__ void reduce_kernel(const double* __restrict__ conds, float* __restrict__ out, int B) {
    __shared__ double sred[4];
    int tid = threadIdx.x;
    double acc = 0.0;
    for (int i = tid; i < B; i += 256) acc += conds[i];
    #pragma unroll
    for (int o = 32; o > 0; o >>= 1) acc += __shfl_xor(acc, o);
    if ((tid & 63) == 0) sred[tid >> 6] = acc;
    __syncthreads();
    if (tid == 0) out[0] = (float)((sred[0] + sred[1] + sred[2] + sred[3]) / (double)B);
}

extern "C" void kernel_launch(void* const* d_in, const int* in_sizes, int n_in,
                              void* d_out, int out_size, void* d_ws, size_t ws_size,
                              hipStream_t stream) {
    const float* DD = (const float*)d_in[0];
    const float* LE = (const float*)d_in[1];
    const float* SC = (const float*)d_in[2];
    float* out = (float*)d_out;
    int B = in_sizes[0] / (N * N);
    double* conds = (double*)d_ws;

    static_assert(SMEM_BYTES <= 160 * 1024, "LDS budget");
    (void)hipFuncSetAttribute((const void*)cond_kernel,
                              hipFuncAttributeMaxDynamicSharedMemorySize, (int)SMEM_BYTES);
    hipLaunchKernelGGL(cond_kernel, dim3(B), dim3(NTHREADS), SMEM_BYTES, stream, DD, LE, SC, conds);
    hipLaunchKernelGGL(reduce_kernel, dim3(1), dim3(256), 0, stream, conds, out, B);
}

// Round 2
// 9082.395 us; speedup vs baseline: 3.1816x; 3.1816x over previous
//
#include <hip/hip_runtime.h>

#define N 128
#define PAD 129
#define NL 8128
#define POWER_IT 24
#define INV_IT 10
#define NTHREADS 256
#define SMEM_BYTES 137280

// LDS layout:
//   Ahi[N*PAD] f32, Alo[N*PAD] f32   (hi/lo split fp64 matrix, 132096 B)
//   dinvd[128] f64                    (1/U[k,k])
//   dmisc[4]   f64                    ([0]=lmax, [1..3]=lmin per inverse wave)
//   fX4[128] float4, fW4[128] float4  (power-iteration vectors, [row][v] packed)
//   iscr[4] int                       (pivot)

static __device__ __forceinline__ double ldD(const float* hi, const float* lo, int idx) {
    return (double)hi[idx] + (double)lo[idx];
}
static __device__ __forceinline__ void stD(float* hi, float* lo, int idx, double v) {
    float h = (float)v;
    hi[idx] = h;
    lo[idx] = (float)(v - (double)h);
}
static __device__ __forceinline__ float hashf(unsigned x) {
    x ^= 2747636419u; x *= 2654435769u; x ^= x >> 16;
    x *= 2654435769u; x ^= x >> 16; x *= 2654435769u;
    return ((float)(x >> 8)) * (1.0f / 16777216.0f) - 0.5f;
}
static __device__ __forceinline__ double readlane_d(double x, int lane) {
    int lo = __builtin_amdgcn_readlane(__double2loint(x), lane);
    int hi = __builtin_amdgcn_readlane(__double2hiint(x), lane);
    return __hiloint2double(hi, lo);
}

// Cholesky of 4x4 Gram (packed upper, 10) -> C = R^{-1} (upper, row-major 4x4). Register-only.
static __device__ __forceinline__ void cholInvC(const double* Gp, double* C) {
    double g[4][4];
    int c = 0;
    #pragma unroll
    for (int a = 0; a < 4; ++a)
        #pragma unroll
        for (int b2 = a; b2 < 4; ++b2) { g[a][b2] = Gp[c]; g[b2][a] = Gp[c]; ++c; }
    double R[4][4];
    #pragma unroll
    for (int i = 0; i < 4; ++i) {
        double d = g[i][i];
        #pragma unroll
        for (int m = 0; m < 4; ++m) if (m < i) d -= R[m][i] * R[m][i];
        d = sqrt(fmax(d, 1e-300));
        R[i][i] = d;
        #pragma unroll
        for (int j = 0; j < 4; ++j) if (j > i) {
            double v = g[i][j];
            #pragma unroll
            for (int m = 0; m < 4; ++m) if (m < i) v -= R[m][i] * R[m][j];
            R[i][j] = v / d;
        }
    }
    #pragma unroll
    for (int j = 3; j >= 0; --j) {
        C[j*4 + j] = 1.0 / R[j][j];
        #pragma unroll
        for (int i = 3; i >= 0; --i) if (i < j) {
            double v = 0.0;
            #pragma unroll
            for (int m = 0; m < 4; ++m) if (m > i && m <= j) v += R[i][m] * C[m*4 + j];
            C[i*4 + j] = -v / R[i][i];
        }
        #pragma unroll
        for (int i = 0; i < 4; ++i) if (i > j) C[i*4 + j] = 0.0;
    }
}

// max eigenvalue of symmetric 4x4 from packed upper Gram (register-only Jacobi)
static __device__ __forceinline__ double jacobi4_lmax(const double* Gp) {
    double g[4][4];
    int c = 0;
    #pragma unroll
    for (int a = 0; a < 4; ++a)
        #pragma unroll
        for (int b2 = a; b2 < 4; ++b2) { g[a][b2] = Gp[c]; g[b2][a] = Gp[c]; ++c; }
    #pragma unroll
    for (int sweep = 0; sweep < 6; ++sweep) {
        #pragma unroll
        for (int p = 0; p < 3; ++p) {
            #pragma unroll
            for (int q = p + 1; q < 4; ++q) {
                double apq = g[p][q];
                double tau = (g[q][q] - g[p][p]) / (2.0 * apq);
                double t = (tau >= 0.0 ? 1.0 : -1.0) / (fabs(tau) + sqrt(1.0 + tau * tau));
                if (fabs(apq) < 1e-280) t = 0.0;
                double cc = 1.0 / sqrt(1.0 + t * t);
                double ss = t * cc;
                #pragma unroll
                for (int r = 0; r < 4; ++r) {
                    double grp = g[r][p], grq = g[r][q];
                    g[r][p] = cc * grp - ss * grq;
                    g[r][q] = ss * grp + cc * grq;
                }
                #pragma unroll
                for (int r = 0; r < 4; ++r) {
                    double gpr = g[p][r], gqr = g[q][r];
                    g[p][r] = cc * gpr - ss * gqr;
                    g[q][r] = ss * gpr + cc * gqr;
                }
            }
        }
    }
    return fmax(fmax(g[0][0], g[1][1]), fmax(g[2][2], g[3][3]));
}

// in-wave CholQR of 2 vectors held as (ya[v]=row l, yb[v]=row l+64)
static __device__ __forceinline__ void cholqr2_d(double ya[2], double yb[2]) {
    double g00 = ya[0]*ya[0] + yb[0]*yb[0];
    double g01 = ya[0]*ya[1] + yb[0]*yb[1];
    double g11 = ya[1]*ya[1] + yb[1]*yb[1];
    #pragma unroll
    for (int o = 32; o > 0; o >>= 1) {
        g00 += __shfl_xor(g00, o);
        g01 += __shfl_xor(g01, o);
        g11 += __shfl_xor(g11, o);
    }
    double r00 = sqrt(fmax(g00, 1e-300));
    double r01 = g01 / r00;
    double r11 = sqrt(fmax(g11 - r01 * r01, fabs(g11) * 1e-26 + 1e-300));
    double c00 = 1.0 / r00, c11 = 1.0 / r11;
    double c01 = -r01 * c00 * c11;
    double a0 = ya[0]*c00,            b0 = yb[0]*c00;
    double a1 = ya[0]*c01 + ya[1]*c11, b1 = yb[0]*c01 + yb[1]*c11;
    ya[0] = a0; yb[0] = b0; ya[1] = a1; yb[1] = b1;
}

#define FMA4(acc, a, v4) { acc[0] += (a)*(v4).x; acc[1] += (a)*(v4).y; acc[2] += (a)*(v4).z; acc[3] += (a)*(v4).w; }

__global__ __launch_bounds__(NTHREADS, 1)
void cond_kernel(const float* __restrict__ DD, const float* __restrict__ LE,
                 const float* __restrict__ SCL, double* __restrict__ conds)
{
    extern __shared__ char smraw[];
    float*  Ahi   = (float*)smraw;
    float*  Alo   = Ahi + N * PAD;
    double* dinvd = (double*)(smraw + 2 * N * PAD * 4);
    double* dmisc = dinvd + 128;
    float4* fX4   = (float4*)(dmisc + 4);
    float4* fW4   = fX4 + 128;
    int*    iscr  = (int*)(fW4 + 128);

    const int tid = threadIdx.x;
    const int b   = blockIdx.x;
    const int wid = tid >> 6;
    const int l   = tid & 63;
    const int r1  = l + 64;
    const double s = (double)SCL[0];
    const float* dd = DD + (size_t)b * (N * N);
    const float* le = LE + (size_t)b * NL;

    // ---- stage DD (fp32 hi; lo implicitly 0 until first stD)
    for (int t = tid; t < (N * N) / 4; t += NTHREADS) {
        float4 dv = reinterpret_cast<const float4*>(dd)[t];
        int elem = t * 4;
        int i = elem >> 7, j = elem & 127;
        float* dst = &Ahi[i * PAD + j];
        dst[0] = dv.x; dst[1] = dv.y; dst[2] = dv.z; dst[3] = dv.w;
    }
    __syncthreads();

    const int pr_ = tid >> 4;   // row-in-16-block
    const int pc_ = tid & 15;   // col group (cols pc_+16e)

    // ---- Pass A: T = D + s * (strict-lower le)^T D, ascending 16-row blocks.
    // T[k,j] depends on raw D rows i>k only -> in-place safe per block.
    for (int KB = 0; KB < N; KB += 16) {
        int k = KB + pr_;
        double acc[8];
        #pragma unroll
        for (int e = 0; e < 8; ++e) acc[e] = 0.0;
        for (int i = k + 1; i < KB + 16; ++i) {           // triangular part (raw D)
            double lv = (double)le[i * (i - 1) / 2 + k];
            #pragma unroll
            for (int e = 0; e < 8; ++e) acc[e] += lv * (double)Ahi[i * PAD + pc_ + 16 * e];
        }
        for (int i = KB + 16; i < N; ++i) {               // common part (raw D)
            double lv = (double)le[i * (i - 1) / 2 + k];
            #pragma unroll
            for (int e = 0; e < 8; ++e) acc[e] += lv * (double)Ahi[i * PAD + pc_ + 16 * e];
        }
        __syncthreads();
        #pragma unroll
        for (int e = 0; e < 8; ++e) {
            int idx = k * PAD + pc_ + 16 * e;
            stD(Ahi, Alo, idx, (double)Ahi[idx] + s * acc[e]);
        }
        __syncthreads();
    }

    // ---- Pass B: P = T + s * (strict-lower le) T, descending 16-row blocks.
    // P[i,j] depends on T rows m<i only -> descending in-place safe per block.
    for (int IB = N - 16; IB >= 0; IB -= 16) {
        int i = IB + pr_;
        int base = i * (i - 1) / 2;
        double acc[8];
        #pragma unroll
        for (int e = 0; e < 8; ++e) acc[e] = 0.0;
        for (int m = 0; m < IB; ++m) {                    // common part (T hi/lo)
            double lv = (double)le[base + m];
            #pragma unroll
            for (int e = 0; e < 8; ++e) acc[e] += lv * ldD(Ahi, Alo, m * PAD + pc_ + 16 * e);
        }
        for (int m = IB; m < i; ++m) {                    // triangular part
            double lv = (double)le[base + m];
            #pragma unroll
            for (int e = 0; e < 8; ++e) acc[e] += lv * ldD(Ahi, Alo, m * PAD + pc_ + 16 * e);
        }
        __syncthreads();
        #pragma unroll
        for (int e = 0; e < 8; ++e) {
            int idx = i * PAD + pc_ + 16 * e;
            stD(Ahi, Alo, idx, ldD(Ahi, Alo, idx) + s * acc[e]);
        }
        __syncthreads();
    }

    // ---- LU with partial pivoting, in place, fp64 hi/lo
    for (int k = 0; k < N - 1; ++k) {
        if (wid == 0) {   // pivot search by wave 0 only, shfl reduce
            float v0 = (l >= k) ? fabsf(Ahi[l * PAD + k]) : -1.0f;
            float v1 = (r1 >= k) ? fabsf(Ahi[r1 * PAD + k]) : -1.0f;
            float vm = v0; int im = l;
            if (v1 > vm) { vm = v1; im = r1; }
            #pragma unroll
            for (int o = 32; o > 0; o >>= 1) {
                float ov = __shfl_xor(vm, o);
                int   oi = __shfl_xor(im, o);
                if (ov > vm) { vm = ov; im = oi; }
            }
            if (l == 0) {
                iscr[0] = im;
                dinvd[k] = 1.0 / ldD(Ahi, Alo, im * PAD + k);
            }
        }
        __syncthreads();
        int p = iscr[0];
        if (p != k) {
            if (tid < N) {
                int a = k * PAD + tid, c = p * PAD + tid;
                float th = Ahi[a], tl = Alo[a];
                Ahi[a] = Ahi[c]; Alo[a] = Alo[c];
                Ahi[c] = th;     Alo[c] = tl;
            }
            __syncthreads();
        }
        double invd = dinvd[k];
        int g8 = tid >> 5, l32 = tid & 31;
        double ukj[4];
        #pragma unroll
        for (int m2 = 0; m2 < 4; ++m2) {
            int j = k + 1 + l32 + 32 * m2;
            ukj[m2] = (j < N) ? ldD(Ahi, Alo, k * PAD + j) : 0.0;
        }
        for (int i = k + 1 + g8; i < N; i += 8) {
            double lik = ldD(Ahi, Alo, i * PAD + k) * invd;
            if (l32 == 0) stD(Ahi, Alo, i * PAD + k, lik);
            #pragma unroll
            for (int m2 = 0; m2 < 4; ++m2) {
                int j = k + 1 + l32 + 32 * m2;
                if (j < N) stD(Ahi, Alo, i * PAD + j, ldD(Ahi, Alo, i * PAD + j) - lik * ukj[m2]);
            }
        }
        __syncthreads();
    }
    if (tid == 0) dinvd[N - 1] = 1.0 / ldD(Ahi, Alo, (N - 1) * PAD + (N - 1));
    __syncthreads();

    // ================= concurrent, barrier-free iteration phase =================
    if (wid == 0) {
        // ---- block-4 power iteration on P^T P = U^T L^T L U (fp32), vectors packed [row][v]
        #pragma unroll
        for (int h = 0; h < 2; ++h) {
            int r = l + 64 * h;
            float4 xv;
            xv.x = hashf(13u + (unsigned)r * 7919u);
            xv.y = hashf(14u + (unsigned)r * 7919u);
            xv.z = hashf(15u + (unsigned)r * 7919u);
            xv.w = hashf(16u + (unsigned)r * 7919u);
            fX4[r] = xv;
        }
        for (int it = 0; it <= POWER_IT; ++it) {
            // t = U x
            float t0[4] = {0,0,0,0}, t1[4] = {0,0,0,0};
            for (int j = 0; j < N; ++j) {
                float a0 = Ahi[l * PAD + j];  a0 = (j >= l)  ? a0 : 0.0f;
                float a1 = Ahi[r1 * PAD + j]; a1 = (j >= r1) ? a1 : 0.0f;
                float4 xv = fX4[j];
                FMA4(t0, a0, xv); FMA4(t1, a1, xv);
            }
            fW4[l]  = make_float4(t0[0], t0[1], t0[2], t0[3]);
            fW4[r1] = make_float4(t1[0], t1[1], t1[2], t1[3]);
            // u = L t (unit diag)
            float u0[4] = {t0[0],t0[1],t0[2],t0[3]}, u1[4] = {t1[0],t1[1],t1[2],t1[3]};
            for (int j = 0; j < N; ++j) {
                float a0 = Ahi[l * PAD + j];  a0 = (j < l)  ? a0 : 0.0f;
                float a1 = Ahi[r1 * PAD + j]; a1 = (j < r1) ? a1 : 0.0f;
                float4 tv = fW4[j];
                FMA4(u0, a0, tv); FMA4(u1, a1, tv);
            }
            if (it == POWER_IT) {
                // Ritz: x orthonormal, G = (LUx)^T (LUx)
                double pr2[10];
                { int c = 0;
                  #pragma unroll
                  for (int v = 0; v < 4; ++v)
                      #pragma unroll
                      for (int w2 = v; w2 < 4; ++w2) {
                          pr2[c] = (double)u0[v] * u0[w2] + (double)u1[v] * u1[w2]; ++c;
                      } }
                #pragma unroll
                for (int o = 32; o > 0; o >>= 1)
                    #pragma unroll
                    for (int c2 = 0; c2 < 10; ++c2) pr2[c2] += __shfl_xor(pr2[c2], o);
                double lmax = jacobi4_lmax(pr2);
                if (l == 0) dmisc[0] = lmax;
                break;
            }
            fW4[l]  = make_float4(u0[0], u0[1], u0[2], u0[3]);
            fW4[r1] = make_float4(u1[0], u1[1], u1[2], u1[3]);
            // w = L^T u
            float w0[4] = {u0[0],u0[1],u0[2],u0[3]}, w1[4] = {u1[0],u1[1],u1[2],u1[3]};
            for (int i = 0; i < N; ++i) {
                float b0 = Ahi[i * PAD + l];  b0 = (i > l)  ? b0 : 0.0f;
                float b1 = Ahi[i * PAD + r1]; b1 = (i > r1) ? b1 : 0.0f;
                float4 uv = fW4[i];
                FMA4(w0, b0, uv); FMA4(w1, b1, uv);
            }
            fW4[l]  = make_float4(w0[0], w0[1], w0[2], w0[3]);
            fW4[r1] = make_float4(w1[0], w1[1], w1[2], w1[3]);
            // z = U^T w
            float z0[4] = {0,0,0,0}, z1[4] = {0,0,0,0};
            for (int i = 0; i < N; ++i) {
                float c0 = Ahi[i * PAD + l];  c0 = (i <= l)  ? c0 : 0.0f;
                float c1 = Ahi[i * PAD + r1]; c1 = (i <= r1) ? c1 : 0.0f;
                float4 wv = fW4[i];
                FMA4(z0, c0, wv); FMA4(z1, c1, wv);
            }
            // CholQR(z) -> x
            double pr2[10];
            { int c = 0;
              #pragma unroll
              for (int v = 0; v < 4; ++v)
                  #pragma unroll
                  for (int w2 = v; w2 < 4; ++w2) {
                      pr2[c] = (double)z0[v] * z0[w2] + (double)z1[v] * z1[w2]; ++c;
                  } }
            #pragma unroll
            for (int o = 32; o > 0; o >>= 1)
                #pragma unroll
                for (int c2 = 0; c2 < 10; ++c2) pr2[c2] += __shfl_xor(pr2[c2], o);
            double C[16];
            cholInvC(pr2, C);
            float xn0[4], xn1[4];
            #pragma unroll
            for (int v = 0; v < 4; ++v) {
                double sa = 0.0, sb = 0.0;
                #pragma unroll
                for (int u2 = 0; u2 <= v; ++u2) {
                    sa += C[u2 * 4 + v] * (double)z0[u2];
                    sb += C[u2 * 4 + v] * (double)z1[u2];
                }
                xn0[v] = (float)sa; xn1[v] = (float)sb;
            }
            fX4[l]  = make_float4(xn0[0], xn0[1], xn0[2], xn0[3]);
            fX4[r1] = make_float4(xn1[0], xn1[1], xn1[2], xn1[3]);
        }
    } else {
        // ---- 3 independent block-2 fp64 inverse iterations (waves 1..3), registers + readlane
        unsigned seed = 1013u * (unsigned)wid;
        double ya[2], yb[2];
        #pragma unroll
        for (int v = 0; v < 2; ++v) {
            ya[v] = (double)hashf(seed + (unsigned)(v * 337 + l * 101 + 7));
            yb[v] = (double)hashf(seed + (unsigned)(v * 337 + r1 * 101 + 7));
        }
        for (int it = 0; it < INV_IT; ++it) {
            // (a) U^T a = y, forward
            for (int i = 0; i < 64; ++i) {
                double invd = dinvd[i];
                double u0 = ldD(Ahi, Alo, i * PAD + l);
                double u1 = ldD(Ahi, Alo, i * PAD + r1);
                bool up0 = (l > i);
                #pragma unroll
                for (int v = 0; v < 2; ++v) {
                    double av = readlane_d(ya[v], i) * invd;
                    double upd = ya[v] - u0 * av;
                    ya[v] = (l == i) ? av : (up0 ? upd : ya[v]);
                    yb[v] -= u1 * av;
                }
            }
            for (int i2 = 0; i2 < 64; ++i2) {
                double invd = dinvd[64 + i2];
                double u1 = ldD(Ahi, Alo, (64 + i2) * PAD + r1);
                bool up1 = (l > i2);
                #pragma unroll
                for (int v = 0; v < 2; ++v) {
                    double av = readlane_d(yb[v], i2) * invd;
                    double upd = yb[v] - u1 * av;
                    yb[v] = (l == i2) ? av : (up1 ? upd : yb[v]);
                }
            }
            // (b) L^T b = a, backward (unit diag)
            for (int j2 = 63; j2 >= 0; --j2) {
                int j = 64 + j2;
                double L0 = ldD(Ahi, Alo, j * PAD + l);
                double L1 = ldD(Ahi, Alo, j * PAD + r1);
                bool m1 = (l < j2);
                #pragma unroll
                for (int v = 0; v < 2; ++v) {
                    double bv = readlane_d(yb[v], j2);
                    ya[v] -= L0 * bv;
                    double upd = yb[v] - L1 * bv;
                    yb[v] = m1 ? upd : yb[v];
                }
            }
            for (int j = 63; j >= 1; --j) {
                double L0 = ldD(Ahi, Alo, j * PAD + l);
                bool m0 = (l < j);
                #pragma unroll
                for (int v = 0; v < 2; ++v) {
                    double bv = readlane_d(ya[v], j);
                    double upd = ya[v] - L0 * bv;
                    ya[v] = m0 ? upd : ya[v];
                }
            }
            // (c) L c = b, forward (unit diag)
            for (int j = 0; j < 64; ++j) {
                double La0 = ldD(Ahi, Alo, l * PAD + j);
                double La1 = ldD(Ahi, Alo, r1 * PAD + j);
                bool m0 = (l > j);
                #pragma unroll
                for (int v = 0; v < 2; ++v) {
                    double cv = readlane_d(ya[v], j);
                    double upd = ya[v] - La0 * cv;
                    ya[v] = m0 ? upd : ya[v];
                    yb[v] -= La1 * cv;
                }
            }
            for (int j2 = 0; j2 < 64; ++j2) {
                double La1 = ldD(Ahi, Alo, r1 * PAD + 64 + j2);
                bool m1 = (l > j2);
                #pragma unroll
                for (int v = 0; v < 2; ++v) {
                    double cv = readlane_d(yb[v], j2);
                    double upd = yb[v] - La1 * cv;
                    yb[v] = m1 ? upd : yb[v];
                }
            }
            // (d) U x = c, backward
            for (int i2 = 63; i2 >= 0; --i2) {
                int i = 64 + i2;
                double invd = dinvd[i];
                double U0 = ldD(Ahi, Alo, l * PAD + i);
                double U1 = ldD(Ahi, Alo, r1 * PAD + i);
                bool m1 = (l < i2);
                #pragma unroll
                for (int v = 0; v < 2; ++v) {
                    double xv = readlane_d(yb[v], i2) * invd;
                    ya[v] -= U0 * xv;
                    double upd = yb[v] - U1 * xv;
                    yb[v] = (l == i2) ? xv : (m1 ? upd : yb[v]);
                }
            }
            for (int i = 63; i >= 0; --i) {
                double invd = dinvd[i];
                double U0 = ldD(Ahi, Alo, l * PAD + i);
                bool m0 = (l < i);
                #pragma unroll
                for (int v = 0; v < 2; ++v) {
                    double xv = readlane_d(ya[v], i) * invd;
                    double upd = ya[v] - U0 * xv;
                    ya[v] = (l == i) ? xv : (m0 ? upd : ya[v]);
                }
            }
            cholqr2_d(ya, yb);
            cholqr2_d(ya, yb);
        }
        // Ritz: z = L U y (fp64, y orthonormal), lmin of 2x2 Gram
        double t0[2] = {0,0}, t1[2] = {0,0};
        for (int j = 0; j < 64; ++j) {
            double u0 = ldD(Ahi, Alo, l * PAD + j);
            u0 = (j >= l) ? u0 : 0.0;
            #pragma unroll
            for (int v = 0; v < 2; ++v) { double yj = readlane_d(ya[v], j); t0[v] += u0 * yj; }
        }
        for (int j2 = 0; j2 < 64; ++j2) {
            int j = 64 + j2;
            double u0 = ldD(Ahi, Alo, l * PAD + j);
            double u1 = ldD(Ahi, Alo, r1 * PAD + j);
            u1 = (j2 >= l) ? u1 : 0.0;
            #pragma unroll
            for (int v = 0; v < 2; ++v) {
                double yj = readlane_d(yb[v], j2);
                t0[v] += u0 * yj; t1[v] += u1 * yj;
            }
        }
        double z0[2] = {t0[0], t0[1]}, z1[2] = {t1[0], t1[1]};
        for (int j = 0; j < 64; ++j) {
            double L0 = ldD(Ahi, Alo, l * PAD + j);
            L0 = (j < l) ? L0 : 0.0;
            double L1 = ldD(Ahi, Alo, r1 * PAD + j);
            #pragma unroll
            for (int v = 0; v < 2; ++v) {
                double tj = readlane_d(t0[v], j);
                z0[v] += L0 * tj; z1[v] += L1 * tj;
            }
        }
        for (int j2 = 0; j2 < 64; ++j2) {
            double L1 = ldD(Ahi, Alo, r1 * PAD + 64 + j2);
            L1 = (j2 < l) ? L1 : 0.0;
            #pragma unroll
            for (int v = 0; v < 2; ++v) {
                double tj = readlane_d(t1[v], j2);
                z1[v] += L1 * tj;
            }
        }
        double g00 = z0[0]*z0[0] + z1[0]*z1[0];
        double g01 = z0[0]*z0[1] + z1[0]*z1[1];
        double g11 = z0[1]*z0[1] + z1[1]*z1[1];
        #pragma unroll
        for (int o = 32; o > 0; o >>= 1) {
            g00 += __shfl_xor(g00, o);
            g01 += __shfl_xor(g01, o);
            g11 += __shfl_xor(g11, o);
        }
        double dif = g00 - g11;
        double lmin = 0.5 * ((g00 + g11) - sqrt(dif * dif + 4.0 * g01 * g01));
        if (l == 0) dmisc[wid] = lmin;
    }
    __syncthreads();
    if (tid == 0) {
        double lmin = fmin(dmisc[1], fmin(dmisc[2], dmisc[3]));
        conds[b] = sqrt(fmax(dmisc[0], 0.0) / fmax(lmin, 1e-290));
    }
}

__global__ void reduce_kernel(const double* __restrict__ conds, float* __restrict__ out, int B) {
    __shared__ double sred[4];
    int tid = threadIdx.x;
    double acc = 0.0;
    for (int i = tid; i < B; i += 256) acc += conds[i];
    #pragma unroll
    for (int o = 32; o > 0; o >>= 1) acc += __shfl_xor(acc, o);
    if ((tid & 63) == 0) sred[tid >> 6] = acc;
    __syncthreads();
    if (tid == 0) out[0] = (float)((sred[0] + sred[1] + sred[2] + sred[3]) / (double)B);
}

extern "C" void kernel_launch(void* const* d_in, const int* in_sizes, int n_in,
                              void* d_out, int out_size, void* d_ws, size_t ws_size,
                              hipStream_t stream) {
    const float* DD = (const float*)d_in[0];
    const float* LE = (const float*)d_in[1];
    const float* SC = (const float*)d_in[2];
    float* out = (float*)d_out;
    int B = in_sizes[0] / (N * N);
    double* conds = (double*)d_ws;

    static_assert(SMEM_BYTES <= 160 * 1024, "LDS budget");
    (void)hipFuncSetAttribute((const void*)cond_kernel,
                              hipFuncAttributeMaxDynamicSharedMemorySize, (int)SMEM_BYTES);
    hipLaunchKernelGGL(cond_kernel, dim3(B), dim3(NTHREADS), SMEM_BYTES, stream, DD, LE, SC, conds);
    hipLaunchKernelGGL(reduce_kernel, dim3(1), dim3(256), 0, stream, conds, out, B);
}